// Round 9
// baseline (87.688 us; speedup 1.0000x reference)
//
#include <hip/hip_runtime.h>
#include <math.h>

namespace {

constexpr int kB = 8;
constexpr int kK = 4096;
constexpr int kC = 1024;
constexpr int kL = 64;            // chunk length along K
constexpr int kNC = kK / kL;      // 64 chunks per batch chain
constexpr int kNBLK = kB * kNC;   // 512 blocks total
constexpr int kTPB = 512;         // 2 channels/thread covers C=1024

constexpr float kClamp = 1.0e4f;
constexpr float kMinD = 0.001f;
constexpr float kMaxD = 0.999f;
constexpr float kEps = 1e-6f;

typedef float f2 __attribute__((ext_vector_type(2)));
typedef _Float16 h2 __attribute__((ext_vector_type(2)));

__device__ __forceinline__ float sanitize(float x) {
  x = (x != x) ? 0.0f : x;                       // NaN -> 0
  return fminf(kClamp, fmaxf(-kClamp, x));       // +-inf and clip -> +-1e4
}

__device__ __forceinline__ float softplusf(float x) {
  return fmaxf(x, 0.0f) + log1pf(expf(-fabsf(x)));
}

__device__ __forceinline__ float decay_of(float logit) {
  return kMinD + (kMaxD - kMinD) / (1.0f + expf(-logit));
}

union f2u {
  unsigned long long u;
  float f[2];
};

// Zero per-chunk flags each call (harness poisons d_ws once to 0xAA and does
// not re-poison between timed replays).
__global__ void k_init(int* __restrict__ flags) {
  const int i = blockIdx.x * blockDim.x + threadIdx.x;
  if (i < kNBLK) flags[i] = 0;
}

// Single-pass chunked scan, decoupled lookback, REGISTER-RESIDENT locals.
// Fabric model (R6): L3-served traffic costs fabric BW like HBM traffic, so
// the Phase-B token re-read (134 MB) was ~28% of runtime. Phase A saves the
// zero-init local scan l_i in packed fp16 REGISTERS; Phase B emits
// out_i = o*l_i + o*d^(i+1)*S with no token re-read.
// - 2 ch/thread x 512 thr: loc[] = 64 VGPR, total ~110 -> no spill (R7 bug 1).
// - Reader-side ACQUIRE fence after spin: forbids carry-load hoisting above
//   the flag observation (R7 bug 2: all-relaxed protocol raced under new
//   codegen). The fence's buffer_inv is now harmless: Phase B reads no
//   global data (registers only), unlike R2 where it nuked token reuse.
// - Writer side: sc1 relaxed carry stores drained by __syncthreads (vmcnt=0)
//   before thread 0's flag store -> carries visible before flag.
__global__ __launch_bounds__(kTPB) void k_scan(
    const float* __restrict__ tokens, const float* __restrict__ state,
    const float* __restrict__ dlog, const float* __restrict__ igr,
    const float* __restrict__ ogr, const float* __restrict__ sbias,
    float* __restrict__ out, float* __restrict__ final_out,
    unsigned long long* __restrict__ carry, int* __restrict__ flags) {
  const int gid = blockIdx.x;
  const int b = gid / kNC;
  const int j = gid - b * kNC;
  const int c0 = threadIdx.x * 2;

  // --- per-channel constrained parameters (2 channels/thread) ---
  const f2 dl = *reinterpret_cast<const f2*>(dlog + c0);
  const f2 ig = *reinterpret_cast<const f2*>(igr + c0);
  const f2 og = *reinterpret_cast<const f2*>(ogr + c0);
  const f2 sb = *reinterpret_cast<const f2*>(sbias + c0);

  const float d0 = decay_of(dl.x), d1 = decay_of(dl.y);
  const float g0 = softplusf(ig.x) + kEps, g1 = softplusf(ig.y) + kEps;
  // b_t = (1-d)*(g*x + bias) = a*x + bb
  const float a0 = (1.0f - d0) * g0, a1 = (1.0f - d1) * g1;
  const float bb0 = (1.0f - d0) * sb.x, bb1 = (1.0f - d1) * sb.y;
  const float o0 = softplusf(og.x) + kEps, o1 = softplusf(og.y) + kEps;

  const float* tp = tokens + (((size_t)b * kK) + (size_t)j * kL) * kC + c0;

  // --- Phase A: zero-init local scan; keep l_i in fp16 registers ---
  h2 loc[kL];  // 64 x 4B = 64 VGPRs; all indices compile-time
  float s0 = 0.0f, s1 = 0.0f;
#pragma unroll
  for (int i0 = 0; i0 < kL; i0 += 8) {
    f2 x[8];
#pragma unroll
    for (int u = 0; u < 8; ++u)
      x[u] = *reinterpret_cast<const f2*>(tp + (size_t)(i0 + u) * kC);
#pragma unroll
    for (int u = 0; u < 8; ++u) {
      s0 = fmaf(d0, s0, fmaf(a0, sanitize(x[u].x), bb0));
      s1 = fmaf(d1, s1, fmaf(a1, sanitize(x[u].y), bb1));
      h2 h; h.x = (_Float16)s0; h.y = (_Float16)s1;
      loc[i0 + u] = h;
    }
  }
  // Exact fp32 chunk aggregate kept live for the final-state output.
  const float cv0 = s0, cv1 = s1;

  // Publish carry (one 8B relaxed agent atomic per thread; sc1 write-through).
  {
    f2u cu; cu.f[0] = cv0; cu.f[1] = cv1;
    __hip_atomic_store(carry + ((size_t)gid * kC + c0) / 2, cu.u,
                       __ATOMIC_RELAXED, __HIP_MEMORY_SCOPE_AGENT);
  }
  __syncthreads();  // every wave drains vmcnt -> all carries visible
  if (threadIdx.x == 0) {
    __hip_atomic_store(flags + gid, 1, __ATOMIC_RELAXED,
                       __HIP_MEMORY_SCOPE_AGENT);
  }

  // --- Lookback: parallel wait (thread t spins on predecessor t's flag) ---
  const int base = b * kNC;
  if (threadIdx.x < j) {
    while (__hip_atomic_load(flags + base + threadIdx.x, __ATOMIC_RELAXED,
                             __HIP_MEMORY_SCOPE_AGENT) == 0) {
      __builtin_amdgcn_s_sleep(2);
    }
  }
  __syncthreads();
  // Acquire: order the Horner carry loads after the observed flags.
  __builtin_amdgcn_fence(__ATOMIC_ACQUIRE, "agent");

  // d^L per channel (L=64 -> 6 squarings)
  float dL0 = d0, dL1 = d1;
#pragma unroll
  for (int i = 0; i < 6; ++i) { dL0 *= dL0; dL1 *= dL1; }

  // Deterministic forward Horner over predecessor aggregates.
  const f2 st = *reinterpret_cast<const f2*>(state + (size_t)b * kC + c0);
  float S0 = st.x, S1 = st.y;
#pragma unroll 8
  for (int p = 0; p < j; ++p) {
    f2u cu;
    cu.u = __hip_atomic_load(carry + ((size_t)(base + p) * kC + c0) / 2,
                             __ATOMIC_RELAXED, __HIP_MEMORY_SCOPE_AGENT);
    S0 = fmaf(dL0, S0, cu.f[0]);
    S1 = fmaf(dL1, S1, cu.f[1]);
  }

  // --- Phase B: out_i = o*l_i + o*d^(i+1)*S — NO token re-read ---
  float* op = out + (((size_t)b * kK) + (size_t)j * kL) * kC + c0;
  float P0 = o0 * S0, P1 = o1 * S1;
#pragma unroll
  for (int i = 0; i < kL; ++i) {
    P0 *= d0; P1 *= d1;  // o*d^(i+1)*S
    const h2 h = loc[i];
    f2 y;
    y.x = fmaf(o0, (float)h.x, P0);
    y.y = fmaf(o1, (float)h.y, P1);
    *reinterpret_cast<f2*>(op + (size_t)i * kC) = y;
  }

  if (j == kNC - 1) {
    // Final state from the EXACT fp32 carry: s_K = d^L*S + carry
    f2 fv;
    fv.x = fmaf(dL0, S0, cv0);
    fv.y = fmaf(dL1, S1, cv1);
    *reinterpret_cast<f2*>(final_out + (size_t)b * kC + c0) = fv;
  }
}

}  // namespace

extern "C" void kernel_launch(void* const* d_in, const int* in_sizes, int n_in,
                              void* d_out, int out_size, void* d_ws, size_t ws_size,
                              hipStream_t stream) {
  const float* tokens = (const float*)d_in[0];
  const float* state  = (const float*)d_in[1];
  const float* dlog   = (const float*)d_in[2];
  const float* igr    = (const float*)d_in[3];
  const float* ogr    = (const float*)d_in[4];
  const float* sbias  = (const float*)d_in[5];

  float* out = (float*)d_out;                     // [B,K,C] outputs
  float* final_out = out + (size_t)kB * kK * kC;  // [B,C] final state

  unsigned long long* carry = (unsigned long long*)d_ws;  // kNBLK*kC floats (2 MiB)
  int* flags = (int*)((char*)d_ws + (size_t)kNBLK * kC * sizeof(float));

  k_init<<<dim3((kNBLK + 255) / 256), 256, 0, stream>>>(flags);
  k_scan<<<dim3(kNBLK), kTPB, 0, stream>>>(tokens, state, dlog, igr, ogr,
                                           sbias, out, final_out, carry, flags);
}